// Round 16
// baseline (138.685 us; speedup 1.0000x reference)
//
#include <hip/hip_runtime.h>
#include <hip/hip_bf16.h>

#define T_ 1024
#define NB 4
#define E_ 256
#define H_ 8
#define D_ 32
#define E3 768

typedef __attribute__((ext_vector_type(4))) short v4s;
typedef __attribute__((ext_vector_type(8))) short v8s;
typedef __attribute__((ext_vector_type(4))) float v4f;

// hardware exp2 (v_exp_f32). __exp2f collides with a glibc math.h symbol.
#define EXP2F(x) __builtin_amdgcn_exp2f(x)

// round-to-nearest-even fp32 -> bf16 bits
__device__ __forceinline__ unsigned short f2bf(float x) {
    union { float f; unsigned int u; } v; v.f = x;
    unsigned int r = v.u + 0x7fffu + ((v.u >> 16) & 1u);
    return (unsigned short)(r >> 16);
}
__device__ __forceinline__ unsigned int pack2(float lo, float hi) {
    return (unsigned int)f2bf(lo) | ((unsigned int)f2bf(hi) << 16);
}

// ---------------------------------------------------------------------------
// Kernel P: prep. blocks 0..255: weight transpose fp32 -> bf16 [N][256].
// blocks 256..767: x fp32 -> bf16 copy. blocks 768..831: RoPE sin/cos
// tables [t][jj] (t 0..1023, jj 0..15), computed ONCE with precise sincosf
// (args up to 1023 rad hit libm's slow reduction path -- R15 post-mortem:
// this was living inside qkv's hot epilogue). grid 832, block 256.
// ---------------------------------------------------------------------------
__global__ __launch_bounds__(256) void prep_kernel(
    const float* __restrict__ w_attn, const float* __restrict__ w_proj,
    const float* __restrict__ x,
    unsigned short* __restrict__ WT, unsigned short* __restrict__ WPT,
    unsigned short* __restrict__ xb,
    float* __restrict__ ctab, float* __restrict__ stab)
{
    const int blk = blockIdx.x;
    if (blk < 256) {
        __shared__ float tile[32][33];
        const int bx = blk & 31, by = blk >> 5;
        const float* src; unsigned short* dst; int N, n0;
        if (bx < 24) { src = w_attn; dst = WT;  N = 768; n0 = bx * 32; }
        else         { src = w_proj; dst = WPT; N = 256; n0 = (bx - 24) * 32; }
        const int k0 = by * 32;
        const int xx = threadIdx.x & 31, y4 = (threadIdx.x >> 5) * 4;
        #pragma unroll
        for (int i = 0; i < 4; ++i)
            tile[y4 + i][xx] = src[(size_t)(k0 + y4 + i) * N + n0 + xx];
        __syncthreads();
        #pragma unroll
        for (int i = 0; i < 4; ++i)
            dst[(size_t)(n0 + y4 + i) * 256 + k0 + xx] = f2bf(tile[xx][y4 + i]);
    } else if (blk < 768) {
        // x convert: 512 blocks x 4096 elements = 2,097,152
        const size_t i = (size_t)(blk - 256) * 4096 + threadIdx.x * 16;
        #pragma unroll
        for (int j = 0; j < 4; ++j) {
            float4 v = *(const float4*)(x + i + j * 4);
            ushort4 o;
            o.x = f2bf(v.x); o.y = f2bf(v.y); o.z = f2bf(v.z); o.w = f2bf(v.w);
            *(ushort4*)(xb + i + j * 4) = o;
        }
    } else {
        // RoPE tables: 64 blocks x 256 = 16384 entries
        const int idx = (blk - 768) * 256 + threadIdx.x;
        const int t = idx >> 4, jj = idx & 15;
        const float invf = __expf(-(float)jj * 0.5756462732485115f);  // 10000^(-jj/16)
        float s, c;
        sincosf((float)t * invf, &s, &c);
        ctab[idx] = c;
        stab[idx] = s;
    }
}

// ---------------------------------------------------------------------------
// Kernel A: qkv = x @ w_attn + b_attn via MFMA, fused RoPE + split stores.
// grid (128 row, 12 col) ROW-FAST: the 12 col-blocks sharing one x row-range
// have ids = row + col*128, all = row (mod 8) -> same XCD -> x rows L2-hot
// (R15 had this backwards). RoPE via precomputed tables (no sincosf).
// block 256 (4 waves x 16 rows). Outputs bf16: Qb,Kb [bh][t][d];
// V window-tiled VW[bh][w][d][32].
// ---------------------------------------------------------------------------
__global__ __launch_bounds__(256) void qkv_mfma_kernel(
    const unsigned short* __restrict__ xb,
    const float* __restrict__ b_attn,
    const unsigned short* __restrict__ WT,
    const float* __restrict__ ctab, const float* __restrict__ stab,
    unsigned short* __restrict__ Qb, unsigned short* __restrict__ Kb,
    unsigned short* __restrict__ VW)
{
    const int tid  = threadIdx.x;
    const int wsb  = tid >> 6;
    const int lane = tid & 63;
    const int g = lane >> 4, c = lane & 15;
    const int m0 = blockIdx.x * 64 + wsb * 16;  // wave's row base (bn,t)
    const int n0 = blockIdx.y * 64;             // col base
    const int bn = m0 >> 10;                    // uniform per block
    const int b  = bn >> 2, nidx = bn & 3;
    const int t_base = m0 & 1023;

    const unsigned short* xrow = xb + ((size_t)(b * T_ + t_base + c) * NB + nidx) * E_;

    v4f acc[4];
    #pragma unroll
    for (int tt = 0; tt < 4; ++tt) acc[tt] = (v4f){0.f, 0.f, 0.f, 0.f};

    #pragma unroll
    for (int k0 = 0; k0 < 256; k0 += 32) {
        v8s afrag = *(const v8s*)(xrow + k0 + 8 * g);
        #pragma unroll
        for (int tt = 0; tt < 4; ++tt) {
            v8s bfrag = *(const v8s*)(WT + (size_t)(n0 + tt * 16 + c) * 256 + k0 + 8 * g);
            acc[tt] = __builtin_amdgcn_mfma_f32_16x16x32_bf16(afrag, bfrag, acc[tt], 0, 0, 0);
        }
    }

    float bias[4];
    #pragma unroll
    for (int tt = 0; tt < 4; ++tt) bias[tt] = b_attn[n0 + tt * 16 + c];

    const int type = n0 >> 8;          // 0=q 1=k 2=v (uniform per block)
    const int nl0  = n0 & 255;

    if (type <= 1) {
        unsigned short* Dst = (type == 0) ? Qb : Kb;
        float sn[4], cs[4];
        #pragma unroll
        for (int r = 0; r < 4; ++r) {
            const int ti = (t_base + 4 * g + r) * 16 + c;
            cs[r] = ctab[ti];
            sn[r] = stab[ti];
        }
        #pragma unroll
        for (int tt = 0; tt < 4; ++tt) {
            const int n_l = nl0 + tt * 16;
            const int h = n_l >> 5, d = (n_l & 31) + c;
            const int bh = bn * 8 + h;
            const float sgn = (tt & 1) ? 1.f : -1.f;
            const int  ptt = tt ^ 1;
            #pragma unroll
            for (int r = 0; r < 4; ++r) {
                float v0 = acc[tt][r] + bias[tt];
                float v1 = acc[ptt][r] + bias[ptt];
                float o  = v0 * cs[r] + sgn * v1 * sn[r];
                int   t  = t_base + 4 * g + r;
                Dst[((size_t)bh * T_ + t) * D_ + d] = f2bf(o);
            }
        }
    } else {
        const int wv_ = t_base >> 5;               // s-window
        const int tw  = (t_base & 31) + 4 * g;     // t within window (4-aligned)
        #pragma unroll
        for (int tt = 0; tt < 4; ++tt) {
            const int n_l = nl0 + tt * 16;
            const int h = n_l >> 5, d = (n_l & 31) + c;
            const int bh = bn * 8 + h;
            ushort4 pk;
            pk.x = f2bf(acc[tt][0] + bias[tt]);
            pk.y = f2bf(acc[tt][1] + bias[tt]);
            pk.z = f2bf(acc[tt][2] + bias[tt]);
            pk.w = f2bf(acc[tt][3] + bias[tt]);
            *(ushort4*)(VW + (((size_t)bh * 32 + wv_) * 32 + d) * 32 + tw) = pk;
        }
    }
}

// ---------------------------------------------------------------------------
// Kernel B: attention with LDS-staged, REUSED K/V windows. (R14 core.)
// grid 512; bh = bx & 63, k = bx >> 6 so the 8 k-blocks sharing one bh's
// K/V are all = bh (mod 8) -> SAME XCD -> K/V fetched into that L2 once
// (R15 layout put them on 8 different XCDs -> 8x L3 refetch; the double
// buffer was hiding L3/HBM latency instead of L2). block 256 (4 waves),
// wave v owns qtile pair {k+8v, k+56-8v}. Fixed-shift softmax (R12).
// ---------------------------------------------------------------------------
#define KMUL   0.2550343f    // (1/sqrt(32)) * log2(e)
#define SHIFTL 11.5415603f   // 8 * log2(e)

__global__ __launch_bounds__(256) void attn_kernel(
    const unsigned short* __restrict__ Qb,
    const unsigned short* __restrict__ Kb,
    const unsigned short* __restrict__ VW,
    unsigned short* __restrict__ Ob)
{
    __shared__ unsigned short ldsK[2][1024];   // 2KB per buf: K rows s0..s0+31
    __shared__ unsigned short ldsV[2][1024];   // 2KB per buf: V window [d][32]

    const int tid  = threadIdx.x;
    const int wv   = tid >> 6;      // wave 0..3
    const int lane = tid & 63;
    const int g = lane >> 4, c = lane & 15;
    const int bx = blockIdx.x;
    const int bh = bx & 63;         // id%8 = bh%8 -> same-bh blocks same XCD
    const int k  = bx >> 6;

    const int qts[2] = { k + 8 * wv, k + 56 - 8 * wv };

    v8s qf[2];
    #pragma unroll
    for (int j = 0; j < 2; ++j)
        qf[j] = *(const v8s*)(Qb + ((size_t)bh * T_ + qts[j] * 16 + c) * D_ + 8 * g);

    v4f o0[2], o1[2];
    float ll[2];
    #pragma unroll
    for (int j = 0; j < 2; ++j) {
        o0[j] = (v4f){0.f, 0.f, 0.f, 0.f};
        o1[j] = (v4f){0.f, 0.f, 0.f, 0.f};
        ll[j] = 0.f;
    }

    const unsigned short* mysrc = (wv < 2)
        ? (Kb + (size_t)bh * T_ * D_ + wv * 512)
        : (VW + (size_t)bh * 32 * 1024 + (wv - 2) * 512);
    const int myoff = (wv & 1) * 512 + lane * 8;

    const int wmax = ((k + 56) >> 1) + 1;

    uint4 stg = *(const uint4*)(mysrc + lane * 8);
    { unsigned short* d0 = (wv < 2) ? &ldsK[0][myoff] : &ldsV[0][myoff];
      *(uint4*)d0 = stg; }
    __syncthreads();

    for (int w = 0; w < wmax; ++w) {
        const bool more = (w + 1) < wmax;
        if (more) stg = *(const uint4*)(mysrc + (size_t)(w + 1) * 1024 + lane * 8);

        const unsigned short* bK = ldsK[w & 1];
        const unsigned short* bV = ldsV[w & 1];

        v8s kfA = *(const v8s*)(bK + c * 32 + 8 * g);
        v8s kfB = *(const v8s*)(bK + 512 + c * 32 + 8 * g);
        v4s vlo0 = *(const v4s*)(bV + c * 32 + 4 * g);
        v4s vhi0 = *(const v4s*)(bV + c * 32 + 16 + 4 * g);
        v4s vlo1 = *(const v4s*)(bV + 512 + c * 32 + 4 * g);
        v4s vhi1 = *(const v4s*)(bV + 512 + c * 32 + 16 + 4 * g);
        v8s vf0, vf1;
        #pragma unroll
        for (int i = 0; i < 4; ++i) {
            vf0[i] = vlo0[i]; vf0[4 + i] = vhi0[i];
            vf1[i] = vlo1[i]; vf1[4 + i] = vhi1[i];
        }

        const int s0 = w * 32;
        #pragma unroll
        for (int j = 0; j < 2; ++j) {
            const int qt  = qts[j];
            const int lim = qt >> 1;
            if (lim < w) continue;              // wave-uniform
            const int q = qt * 16 + c;

            v4f zero = {0.f, 0.f, 0.f, 0.f};
            v4f sA = __builtin_amdgcn_mfma_f32_16x16x32_bf16(kfA, qf[j], zero, 0, 0, 0);
            v4f sB = __builtin_amdgcn_mfma_f32_16x16x32_bf16(kfB, qf[j], zero, 0, 0, 0);

            const bool diag = (lim == w);
            float p[8];
            #pragma unroll
            for (int r = 0; r < 4; ++r) {
                float pa = EXP2F(fmaf(sA[r], KMUL, -SHIFTL));
                float pb = EXP2F(fmaf(sB[r], KMUL, -SHIFTL));
                if (diag) {
                    if (s0 + 4 * g + r > q)      pa = 0.f;
                    if (s0 + 16 + 4 * g + r > q) pb = 0.f;
                }
                p[r] = pa; p[4 + r] = pb;
                ll[j] += pa + pb;
            }
            union { v8s v; uint4 u; } pu;
            pu.u.x = pack2(p[0], p[1]);
            pu.u.y = pack2(p[2], p[3]);
            pu.u.z = pack2(p[4], p[5]);
            pu.u.w = pack2(p[6], p[7]);
            o0[j] = __builtin_amdgcn_mfma_f32_16x16x32_bf16(pu.v, vf0, o0[j], 0, 0, 0);
            o1[j] = __builtin_amdgcn_mfma_f32_16x16x32_bf16(pu.v, vf1, o1[j], 0, 0, 0);
        }

        if (more) {
            unsigned short* dN = (wv < 2) ? &ldsK[(w + 1) & 1][myoff]
                                          : &ldsV[(w + 1) & 1][myoff];
            *(uint4*)dN = stg;
        }
        __syncthreads();
    }

    const int bn = bh >> 3, h = bh & 7;
    #pragma unroll
    for (int j = 0; j < 2; ++j) {
        float l_s = ll[j];
        l_s += __shfl_xor(l_s, 16, 64);
        l_s += __shfl_xor(l_s, 32, 64);
        float linv = 1.0f / l_s;
        float lr[4];
        #pragma unroll
        for (int r = 0; r < 4; ++r) lr[r] = __shfl(linv, 4 * g + r, 64);
        const int q0 = qts[j] * 16;
        #pragma unroll
        for (int r = 0; r < 4; ++r) {
            unsigned short* Orow = Ob + ((size_t)bn * T_ + q0 + 4 * g + r) * E_ + h * D_;
            Orow[c]      = f2bf(o0[j][r] * lr[r]);
            Orow[16 + c] = f2bf(o1[j][r] * lr[r]);
        }
    }
}

// ---------------------------------------------------------------------------
// Kernel C: out = O @ w_proj + b_proj via MFMA, transposed fp32 store to
// (B,T,N,E). grid (128, 4) row-fast (same-row blocks same XCD), block 256.
// ---------------------------------------------------------------------------
__global__ __launch_bounds__(256) void proj_mfma_kernel(
    const unsigned short* __restrict__ Ob,
    const unsigned short* __restrict__ WPT,
    const float* __restrict__ b_proj,
    float* __restrict__ out)
{
    const int tid  = threadIdx.x;
    const int wsb  = tid >> 6;
    const int lane = tid & 63;
    const int g = lane >> 4, c = lane & 15;
    const int m0 = blockIdx.x * 64 + wsb * 16;
    const int n0 = blockIdx.y * 64;
    const int bn = m0 >> 10;
    const int b  = bn >> 2, nidx = bn & 3;
    const int t_base = m0 & 1023;

    const unsigned short* arow = Ob + ((size_t)bn * T_ + t_base + c) * E_;

    v4f acc[4];
    #pragma unroll
    for (int tt = 0; tt < 4; ++tt) acc[tt] = (v4f){0.f, 0.f, 0.f, 0.f};

    #pragma unroll
    for (int s = 0; s < 8; ++s) {
        v8s afrag = *(const v8s*)(arow + s * 32 + 8 * g);
        #pragma unroll
        for (int tt = 0; tt < 4; ++tt) {
            v8s bfrag = *(const v8s*)(WPT + (size_t)(n0 + tt * 16 + c) * 256 + s * 32 + 8 * g);
            acc[tt] = __builtin_amdgcn_mfma_f32_16x16x32_bf16(afrag, bfrag, acc[tt], 0, 0, 0);
        }
    }

    #pragma unroll
    for (int tt = 0; tt < 4; ++tt) {
        const int n = n0 + tt * 16 + c;
        const float bp = b_proj[n];
        #pragma unroll
        for (int r = 0; r < 4; ++r) {
            const int t = t_base + 4 * g + r;
            out[((size_t)(b * T_ + t) * NB + nidx) * E_ + n] = acc[tt][r] + bp;
        }
    }
}

// ---------------------------------------------------------------------------
extern "C" void kernel_launch(void* const* d_in, const int* in_sizes, int n_in,
                              void* d_out, int out_size, void* d_ws, size_t ws_size,
                              hipStream_t stream)
{
    const float* x      = (const float*)d_in[0];
    const float* w_attn = (const float*)d_in[1];
    const float* b_attn = (const float*)d_in[2];
    const float* w_proj = (const float*)d_in[3];
    const float* b_proj = (const float*)d_in[4];
    float* out = (float*)d_out;

    // ws (ushort units): Qb/Kb/VW/Ob/xb 2M each; WT 768*256; WPT 256*256;
    // then fp32 RoPE tables (16K each).
    unsigned short* Qb  = (unsigned short*)d_ws;
    unsigned short* Kb  = Qb + 2097152;
    unsigned short* VW  = Kb + 2097152;
    unsigned short* Ob  = VW + 2097152;
    unsigned short* xb  = Ob + 2097152;
    unsigned short* WT  = xb + 2097152;
    unsigned short* WPT = WT + 196608;
    float* ctab = (float*)(WPT + 65536);
    float* stab = ctab + 16384;

    prep_kernel<<<832, 256, 0, stream>>>(w_attn, w_proj, x, WT, WPT, xb, ctab, stab);
    qkv_mfma_kernel<<<dim3(128, 12), 256, 0, stream>>>(xb, b_attn, WT, ctab, stab, Qb, Kb, VW);
    attn_kernel<<<512, 256, 0, stream>>>(Qb, Kb, VW, Ob);
    proj_mfma_kernel<<<dim3(128, 4), 256, 0, stream>>>(Ob, WPT, b_proj, out);
}

// Round 17
// 136.732 us; speedup vs baseline: 1.0143x; 1.0143x over previous
//
#include <hip/hip_runtime.h>
#include <hip/hip_bf16.h>

#define T_ 1024
#define NB 4
#define E_ 256
#define H_ 8
#define D_ 32
#define E3 768

typedef __attribute__((ext_vector_type(4))) short v4s;
typedef __attribute__((ext_vector_type(8))) short v8s;
typedef __attribute__((ext_vector_type(4))) float v4f;

// hardware exp2 (v_exp_f32). __exp2f collides with a glibc math.h symbol.
#define EXP2F(x) __builtin_amdgcn_exp2f(x)

// round-to-nearest-even fp32 -> bf16 bits
__device__ __forceinline__ unsigned short f2bf(float x) {
    union { float f; unsigned int u; } v; v.f = x;
    unsigned int r = v.u + 0x7fffu + ((v.u >> 16) & 1u);
    return (unsigned short)(r >> 16);
}
__device__ __forceinline__ unsigned int pack2(float lo, float hi) {
    return (unsigned int)f2bf(lo) | ((unsigned int)f2bf(hi) << 16);
}

// ---------------------------------------------------------------------------
// Kernel P: prep. blocks 0..255: weight transpose fp32 -> bf16 [N][256].
// blocks 256..767: x fp32 -> bf16 copy. blocks 768..831: RoPE sin/cos
// tables [t][jj], computed once with precise sincosf. grid 832, block 256.
// ---------------------------------------------------------------------------
__global__ __launch_bounds__(256) void prep_kernel(
    const float* __restrict__ w_attn, const float* __restrict__ w_proj,
    const float* __restrict__ x,
    unsigned short* __restrict__ WT, unsigned short* __restrict__ WPT,
    unsigned short* __restrict__ xb,
    float* __restrict__ ctab, float* __restrict__ stab)
{
    const int blk = blockIdx.x;
    if (blk < 256) {
        __shared__ float tile[32][33];
        const int bx = blk & 31, by = blk >> 5;
        const float* src; unsigned short* dst; int N, n0;
        if (bx < 24) { src = w_attn; dst = WT;  N = 768; n0 = bx * 32; }
        else         { src = w_proj; dst = WPT; N = 256; n0 = (bx - 24) * 32; }
        const int k0 = by * 32;
        const int xx = threadIdx.x & 31, y4 = (threadIdx.x >> 5) * 4;
        #pragma unroll
        for (int i = 0; i < 4; ++i)
            tile[y4 + i][xx] = src[(size_t)(k0 + y4 + i) * N + n0 + xx];
        __syncthreads();
        #pragma unroll
        for (int i = 0; i < 4; ++i)
            dst[(size_t)(n0 + y4 + i) * 256 + k0 + xx] = f2bf(tile[xx][y4 + i]);
    } else if (blk < 768) {
        // x convert: 512 blocks x 4096 elements = 2,097,152
        const size_t i = (size_t)(blk - 256) * 4096 + threadIdx.x * 16;
        #pragma unroll
        for (int j = 0; j < 4; ++j) {
            float4 v = *(const float4*)(x + i + j * 4);
            ushort4 o;
            o.x = f2bf(v.x); o.y = f2bf(v.y); o.z = f2bf(v.z); o.w = f2bf(v.w);
            *(ushort4*)(xb + i + j * 4) = o;
        }
    } else {
        // RoPE tables: 64 blocks x 256 = 16384 entries
        const int idx = (blk - 768) * 256 + threadIdx.x;
        const int t = idx >> 4, jj = idx & 15;
        const float invf = __expf(-(float)jj * 0.5756462732485115f);  // 10000^(-jj/16)
        float s, c;
        sincosf((float)t * invf, &s, &c);
        ctab[idx] = c;
        stab[idx] = s;
    }
}

// ---------------------------------------------------------------------------
// Kernel A: qkv = x @ w_attn + b_attn via MFMA, fused RoPE + split stores.
// grid (128 row, 12 col) row-fast (same-x-row blocks on same XCD). RoPE via
// tables. block 256 (4 waves x 16 rows). Outputs bf16: Qb,Kb [bh][t][d];
// V window-tiled VW[bh][w][d][32].   (R16, unchanged.)
// ---------------------------------------------------------------------------
__global__ __launch_bounds__(256) void qkv_mfma_kernel(
    const unsigned short* __restrict__ xb,
    const float* __restrict__ b_attn,
    const unsigned short* __restrict__ WT,
    const float* __restrict__ ctab, const float* __restrict__ stab,
    unsigned short* __restrict__ Qb, unsigned short* __restrict__ Kb,
    unsigned short* __restrict__ VW)
{
    const int tid  = threadIdx.x;
    const int wsb  = tid >> 6;
    const int lane = tid & 63;
    const int g = lane >> 4, c = lane & 15;
    const int m0 = blockIdx.x * 64 + wsb * 16;  // wave's row base (bn,t)
    const int n0 = blockIdx.y * 64;             // col base
    const int bn = m0 >> 10;                    // uniform per block
    const int b  = bn >> 2, nidx = bn & 3;
    const int t_base = m0 & 1023;

    const unsigned short* xrow = xb + ((size_t)(b * T_ + t_base + c) * NB + nidx) * E_;

    v4f acc[4];
    #pragma unroll
    for (int tt = 0; tt < 4; ++tt) acc[tt] = (v4f){0.f, 0.f, 0.f, 0.f};

    #pragma unroll
    for (int k0 = 0; k0 < 256; k0 += 32) {
        v8s afrag = *(const v8s*)(xrow + k0 + 8 * g);
        #pragma unroll
        for (int tt = 0; tt < 4; ++tt) {
            v8s bfrag = *(const v8s*)(WT + (size_t)(n0 + tt * 16 + c) * 256 + k0 + 8 * g);
            acc[tt] = __builtin_amdgcn_mfma_f32_16x16x32_bf16(afrag, bfrag, acc[tt], 0, 0, 0);
        }
    }

    float bias[4];
    #pragma unroll
    for (int tt = 0; tt < 4; ++tt) bias[tt] = b_attn[n0 + tt * 16 + c];

    const int type = n0 >> 8;          // 0=q 1=k 2=v (uniform per block)
    const int nl0  = n0 & 255;

    if (type <= 1) {
        unsigned short* Dst = (type == 0) ? Qb : Kb;
        float sn[4], cs[4];
        #pragma unroll
        for (int r = 0; r < 4; ++r) {
            const int ti = (t_base + 4 * g + r) * 16 + c;
            cs[r] = ctab[ti];
            sn[r] = stab[ti];
        }
        #pragma unroll
        for (int tt = 0; tt < 4; ++tt) {
            const int n_l = nl0 + tt * 16;
            const int h = n_l >> 5, d = (n_l & 31) + c;
            const int bh = bn * 8 + h;
            const float sgn = (tt & 1) ? 1.f : -1.f;
            const int  ptt = tt ^ 1;
            #pragma unroll
            for (int r = 0; r < 4; ++r) {
                float v0 = acc[tt][r] + bias[tt];
                float v1 = acc[ptt][r] + bias[ptt];
                float o  = v0 * cs[r] + sgn * v1 * sn[r];
                int   t  = t_base + 4 * g + r;
                Dst[((size_t)bh * T_ + t) * D_ + d] = f2bf(o);
            }
        }
    } else {
        const int wv_ = t_base >> 5;               // s-window
        const int tw  = (t_base & 31) + 4 * g;     // t within window (4-aligned)
        #pragma unroll
        for (int tt = 0; tt < 4; ++tt) {
            const int n_l = nl0 + tt * 16;
            const int h = n_l >> 5, d = (n_l & 31) + c;
            const int bh = bn * 8 + h;
            ushort4 pk;
            pk.x = f2bf(acc[tt][0] + bias[tt]);
            pk.y = f2bf(acc[tt][1] + bias[tt]);
            pk.z = f2bf(acc[tt][2] + bias[tt]);
            pk.w = f2bf(acc[tt][3] + bias[tt]);
            *(ushort4*)(VW + (((size_t)bh * 32 + wv_) * 32 + d) * 32 + tw) = pk;
        }
    }
}

// ---------------------------------------------------------------------------
// Kernel B: attention, LDS-staged K/V, TWO windows per barrier.
// grid 512; bh = bx & 63 (same-bh blocks same XCD), k = bx >> 6.
// block 256 (4 waves); wave v owns qtile pair {k+8v, k+56-8v}.
// Each barrier iteration stages a 64-s superwindow (4KB K + 4KB V: every
// thread writes 2x16B) into a double buffer and computes both sub-windows
// -- halves the barrier count (~31 -> ~16) and doubles the compute
// available to hide the prefetch (R16 post-mortem: barrier-chain-bound).
// Fixed-shift softmax (R12): additive, no cross-lane ops in the loop.
// ---------------------------------------------------------------------------
#define KMUL   0.2550343f    // (1/sqrt(32)) * log2(e)
#define SHIFTL 11.5415603f   // 8 * log2(e)

__global__ __launch_bounds__(256) void attn_kernel(
    const unsigned short* __restrict__ Qb,
    const unsigned short* __restrict__ Kb,
    const unsigned short* __restrict__ VW,
    unsigned short* __restrict__ Ob)
{
    __shared__ unsigned short ldsK[2][2048];   // 4KB per buf: K rows s0..s0+63
    __shared__ unsigned short ldsV[2][2048];   // 4KB per buf: V 2 windows [d][32]

    const int tid  = threadIdx.x;
    const int wv   = tid >> 6;      // wave 0..3
    const int lane = tid & 63;
    const int g = lane >> 4, c = lane & 15;
    const int bx = blockIdx.x;
    const int bh = bx & 63;         // id%8 = bh%8 -> same-bh blocks same XCD
    const int k  = bx >> 6;

    const int qts[2] = { k + 8 * wv, k + 56 - 8 * wv };

    v8s qf[2];
    #pragma unroll
    for (int j = 0; j < 2; ++j)
        qf[j] = *(const v8s*)(Qb + ((size_t)bh * T_ + qts[j] * 16 + c) * D_ + 8 * g);

    v4f o0[2], o1[2];
    float ll[2];
    #pragma unroll
    for (int j = 0; j < 2; ++j) {
        o0[j] = (v4f){0.f, 0.f, 0.f, 0.f};
        o1[j] = (v4f){0.f, 0.f, 0.f, 0.f};
        ll[j] = 0.f;
    }

    const unsigned short* Ksrc = Kb + (size_t)bh * T_ * D_;    // [t][d], 64KB
    const unsigned short* Vsrc = VW + (size_t)bh * 32 * 1024;  // [w][d][32]

    const int wmax = ((k + 56) >> 1) + 1;   // sub-windows (29..32)
    const int WMAX = (wmax + 1) >> 1;       // superwindows (15..16)

    // preload superwindow 0
    uint4 kstg = *(const uint4*)(Ksrc + tid * 8);
    uint4 vstg = *(const uint4*)(Vsrc + tid * 8);
    *(uint4*)&ldsK[0][tid * 8] = kstg;
    *(uint4*)&ldsV[0][tid * 8] = vstg;
    __syncthreads();

    for (int W = 0; W < WMAX; ++W) {
        const bool more = (W + 1) < WMAX;
        if (more) {
            kstg = *(const uint4*)(Ksrc + (size_t)(W + 1) * 2048 + tid * 8);
            vstg = *(const uint4*)(Vsrc + (size_t)(W + 1) * 2048 + tid * 8);
        }
        const unsigned short* bK = ldsK[W & 1];
        const unsigned short* bV = ldsV[W & 1];

        #pragma unroll
        for (int sub = 0; sub < 2; ++sub) {
            const int w = 2 * W + sub;
            if (w >= wmax) break;               // uniform
            const unsigned short* sK = bK + sub * 1024;
            const unsigned short* sV = bV + sub * 1024;

            v8s kfA = *(const v8s*)(sK + c * 32 + 8 * g);
            v8s kfB = *(const v8s*)(sK + 512 + c * 32 + 8 * g);
            v4s vlo0 = *(const v4s*)(sV + c * 32 + 4 * g);
            v4s vhi0 = *(const v4s*)(sV + c * 32 + 16 + 4 * g);
            v4s vlo1 = *(const v4s*)(sV + 512 + c * 32 + 4 * g);
            v4s vhi1 = *(const v4s*)(sV + 512 + c * 32 + 16 + 4 * g);
            v8s vf0, vf1;
            #pragma unroll
            for (int i = 0; i < 4; ++i) {
                vf0[i] = vlo0[i]; vf0[4 + i] = vhi0[i];
                vf1[i] = vlo1[i]; vf1[4 + i] = vhi1[i];
            }

            const int s0 = w * 32;
            #pragma unroll
            for (int j = 0; j < 2; ++j) {
                const int qt  = qts[j];
                const int lim = qt >> 1;
                if (lim < w) continue;          // wave-uniform
                const int q = qt * 16 + c;

                v4f zero = {0.f, 0.f, 0.f, 0.f};
                v4f sA = __builtin_amdgcn_mfma_f32_16x16x32_bf16(kfA, qf[j], zero, 0, 0, 0);
                v4f sB = __builtin_amdgcn_mfma_f32_16x16x32_bf16(kfB, qf[j], zero, 0, 0, 0);

                const bool diag = (lim == w);
                float p[8];
                #pragma unroll
                for (int r = 0; r < 4; ++r) {
                    float pa = EXP2F(fmaf(sA[r], KMUL, -SHIFTL));
                    float pb = EXP2F(fmaf(sB[r], KMUL, -SHIFTL));
                    if (diag) {
                        if (s0 + 4 * g + r > q)      pa = 0.f;
                        if (s0 + 16 + 4 * g + r > q) pb = 0.f;
                    }
                    p[r] = pa; p[4 + r] = pb;
                    ll[j] += pa + pb;
                }
                union { v8s v; uint4 u; } pu;
                pu.u.x = pack2(p[0], p[1]);
                pu.u.y = pack2(p[2], p[3]);
                pu.u.z = pack2(p[4], p[5]);
                pu.u.w = pack2(p[6], p[7]);
                o0[j] = __builtin_amdgcn_mfma_f32_16x16x32_bf16(pu.v, vf0, o0[j], 0, 0, 0);
                o1[j] = __builtin_amdgcn_mfma_f32_16x16x32_bf16(pu.v, vf1, o1[j], 0, 0, 0);
            }
        }

        if (more) {
            *(uint4*)&ldsK[(W + 1) & 1][tid * 8] = kstg;
            *(uint4*)&ldsV[(W + 1) & 1][tid * 8] = vstg;
        }
        __syncthreads();
    }

    const int bn = bh >> 3, h = bh & 7;
    #pragma unroll
    for (int j = 0; j < 2; ++j) {
        float l_s = ll[j];
        l_s += __shfl_xor(l_s, 16, 64);
        l_s += __shfl_xor(l_s, 32, 64);
        float linv = 1.0f / l_s;
        float lr[4];
        #pragma unroll
        for (int r = 0; r < 4; ++r) lr[r] = __shfl(linv, 4 * g + r, 64);
        const int q0 = qts[j] * 16;
        #pragma unroll
        for (int r = 0; r < 4; ++r) {
            unsigned short* Orow = Ob + ((size_t)bn * T_ + q0 + 4 * g + r) * E_ + h * D_;
            Orow[c]      = f2bf(o0[j][r] * lr[r]);
            Orow[16 + c] = f2bf(o1[j][r] * lr[r]);
        }
    }
}

// ---------------------------------------------------------------------------
// Kernel C: out = O @ w_proj + b_proj via MFMA, transposed fp32 store to
// (B,T,N,E). grid (128, 4) row-fast, block 256.   (R16, unchanged.)
// ---------------------------------------------------------------------------
__global__ __launch_bounds__(256) void proj_mfma_kernel(
    const unsigned short* __restrict__ Ob,
    const unsigned short* __restrict__ WPT,
    const float* __restrict__ b_proj,
    float* __restrict__ out)
{
    const int tid  = threadIdx.x;
    const int wsb  = tid >> 6;
    const int lane = tid & 63;
    const int g = lane >> 4, c = lane & 15;
    const int m0 = blockIdx.x * 64 + wsb * 16;
    const int n0 = blockIdx.y * 64;
    const int bn = m0 >> 10;
    const int b  = bn >> 2, nidx = bn & 3;
    const int t_base = m0 & 1023;

    const unsigned short* arow = Ob + ((size_t)bn * T_ + t_base + c) * E_;

    v4f acc[4];
    #pragma unroll
    for (int tt = 0; tt < 4; ++tt) acc[tt] = (v4f){0.f, 0.f, 0.f, 0.f};

    #pragma unroll
    for (int s = 0; s < 8; ++s) {
        v8s afrag = *(const v8s*)(arow + s * 32 + 8 * g);
        #pragma unroll
        for (int tt = 0; tt < 4; ++tt) {
            v8s bfrag = *(const v8s*)(WPT + (size_t)(n0 + tt * 16 + c) * 256 + s * 32 + 8 * g);
            acc[tt] = __builtin_amdgcn_mfma_f32_16x16x32_bf16(afrag, bfrag, acc[tt], 0, 0, 0);
        }
    }

    #pragma unroll
    for (int tt = 0; tt < 4; ++tt) {
        const int n = n0 + tt * 16 + c;
        const float bp = b_proj[n];
        #pragma unroll
        for (int r = 0; r < 4; ++r) {
            const int t = t_base + 4 * g + r;
            out[((size_t)(b * T_ + t) * NB + nidx) * E_ + n] = acc[tt][r] + bp;
        }
    }
}

// ---------------------------------------------------------------------------
extern "C" void kernel_launch(void* const* d_in, const int* in_sizes, int n_in,
                              void* d_out, int out_size, void* d_ws, size_t ws_size,
                              hipStream_t stream)
{
    const float* x      = (const float*)d_in[0];
    const float* w_attn = (const float*)d_in[1];
    const float* b_attn = (const float*)d_in[2];
    const float* w_proj = (const float*)d_in[3];
    const float* b_proj = (const float*)d_in[4];
    float* out = (float*)d_out;

    // ws (ushort units): Qb/Kb/VW/Ob/xb 2M each; WT 768*256; WPT 256*256;
    // then fp32 RoPE tables (16K each).
    unsigned short* Qb  = (unsigned short*)d_ws;
    unsigned short* Kb  = Qb + 2097152;
    unsigned short* VW  = Kb + 2097152;
    unsigned short* Ob  = VW + 2097152;
    unsigned short* xb  = Ob + 2097152;
    unsigned short* WT  = xb + 2097152;
    unsigned short* WPT = WT + 196608;
    float* ctab = (float*)(WPT + 65536);
    float* stab = ctab + 16384;

    prep_kernel<<<832, 256, 0, stream>>>(w_attn, w_proj, x, WT, WPT, xb, ctab, stab);
    qkv_mfma_kernel<<<dim3(128, 12), 256, 0, stream>>>(xb, b_attn, WT, ctab, stab, Qb, Kb, VW);
    attn_kernel<<<512, 256, 0, stream>>>(Qb, Kb, VW, Ob);
    proj_mfma_kernel<<<dim3(128, 4), 256, 0, stream>>>(Ob, WPT, b_proj, out);
}